// Round 17
// baseline (167.096 us; speedup 1.0000x reference)
//
#include <hip/hip_runtime.h>
#include <hip/hip_bf16.h>
#include <math.h>

#define N_NODES 80000
#define N_EDGES 1280000
#define IN_C 128
#define HID_C 64
#define OUT_C 40

// Bucketed binning: bucket = dst >> 8 (256 nodes per bucket)
#define KB 313            // ceil(80000 / 256)
#define BK_CAP 4600       // per-bucket total cap (mean 4090, sigma ~64 -> 8 sigma)
#define SEG 16            // counter shards per bucket (g = blockIdx & 15)
#define GCAP 416          // per-(bucket,shard) slot cap (mean 256, sigma ~16 -> 10 sigma)
#define BK2 (SEG * GCAP)  // 6656 slots per bucket in gbuf
#define EPT_A 8           // edges per thread in phase A (512 thr -> 4096 per WG)
#define NBLK_A 313        // ceil(1280000 / 4096)
#define NBLK_G1 625       // N_NODES / 128 (8 waves x 16 nodes per block)

// ---- bf16 helpers (storage bf16, math fp32) ----
__device__ __forceinline__ float bf_lo(unsigned u) {
    union { unsigned i; float f; } c; c.i = u << 16; return c.f;
}
__device__ __forceinline__ float bf_hi(unsigned u) {
    union { unsigned i; float f; } c; c.i = u & 0xffff0000u; return c.f;
}
__device__ __forceinline__ unsigned pack_bf2(float a, float b) {  // RTNE
    union { float f; unsigned i; } ca, cb; ca.f = a; cb.f = b;
    unsigned ra = (ca.i + 0x7fffu + ((ca.i >> 16) & 1u)) >> 16;
    unsigned rb = (cb.i + 0x7fffu + ((cb.i >> 16) & 1u)) >> 16;
    return ra | (rb << 16);
}

typedef short v8s __attribute__((ext_vector_type(8)));   // 8 bf16 = 4 VGPR
typedef float v4f __attribute__((ext_vector_type(4)));
typedef float v2f __attribute__((ext_vector_type(2)));
union U16 { uint4 u; v8s s; };

// wave-inclusive scan (64 lanes, no barriers)
__device__ __forceinline__ int wave_incl_scan(int v, int lane) {
#pragma unroll
    for (int o = 1; o < 64; o <<= 1) {
        const int t = __shfl_up(v, o, 64);
        if (lane >= o) v += t;
    }
    return v;
}

// ======== prep: W1^T, W2^T to bf16 + zero bcnt16 (20 blocks) ========
__global__ void prep_w_kernel(const float* __restrict__ W1, const float* __restrict__ W2,
                              unsigned* __restrict__ w1t, unsigned* __restrict__ w2t,
                              int* __restrict__ bcnt16) {
    const int g = blockIdx.x * 256 + threadIdx.x;     // 0..5119
    if (g < SEG * KB) bcnt16[g] = 0;
    if (g < 4096) {   // w1t
        const int wcol = g >> 6, kk = g & 63;
        w1t[g] = pack_bf2(W1[(2 * kk) * HID_C + wcol], W1[(2 * kk + 1) * HID_C + wcol]);
    }
    if (g < 1536) {   // w2t
        const int wcol = g >> 5, kk = g & 31;
        w2t[g] = (wcol < OUT_C)
            ? pack_bf2(W2[(2 * kk) * OUT_C + wcol], W2[(2 * kk + 1) * OUT_C + wcol])
            : 0u;
    }
}

// ========== Combined launch: blocks [0,NBLK_A) bin edges; rest do GEMM1 ==========
// r12-proven configuration: scalar strided edge loads (issue-order interleave
// with rank atomics), rank trick (single LDS-atomic pass), staged gbuf writes
// (LDS stage/gaddr -> coalesced 64-lane burst sweep).
__global__ __launch_bounds__(512) void binA_gemm1_kernel(const int* __restrict__ src,
                                                         const int* __restrict__ dst,
                                                         int* __restrict__ bcnt16,
                                                         int* __restrict__ gbuf,
                                                         const float* __restrict__ x,
                                                         const unsigned* __restrict__ w1t,
                                                         unsigned* __restrict__ h1f) {
    if (blockIdx.x >= NBLK_A) {
        const int tid = threadIdx.x;
        const int wave = tid >> 6, lane = tid & 63;
        const int nl = lane & 15, quad = lane >> 4;
        const int node = ((blockIdx.x - NBLK_A) * 8 + wave) * 16 + nl;

        float4 xv[8];
#pragma unroll
        for (int kit = 0; kit < 4; ++kit) {
            const float* xp = x + (size_t)node * IN_C + kit * 32 + quad * 8;
            xv[kit * 2]     = *(const float4*)xp;
            xv[kit * 2 + 1] = *(const float4*)(xp + 4);
        }

        v4f acc[4];
#pragma unroll
        for (int q = 0; q < 4; ++q) acc[q] = (v4f){0.f, 0.f, 0.f, 0.f};

#pragma unroll
        for (int kit = 0; kit < 4; ++kit) {
            const float4 lo = xv[kit * 2], hi = xv[kit * 2 + 1];
            U16 bu;
            bu.u.x = pack_bf2(lo.x, lo.y); bu.u.y = pack_bf2(lo.z, lo.w);
            bu.u.z = pack_bf2(hi.x, hi.y); bu.u.w = pack_bf2(hi.z, hi.w);
#pragma unroll
            for (int mt = 0; mt < 4; ++mt) {
                U16 au;
                au.u = *(const uint4*)(w1t + ((mt * 16 + nl) * 64 + kit * 16 + quad * 4));
                acc[mt] = __builtin_amdgcn_mfma_f32_16x16x32_bf16(au.s, bu.s, acc[mt], 0, 0, 0);
            }
        }
#pragma unroll
        for (int mt = 0; mt < 4; ++mt) {
            int u = 0;
            u = __builtin_amdgcn_cvt_pk_fp8_f32(acc[mt][0], acc[mt][1], u, false);
            u = __builtin_amdgcn_cvt_pk_fp8_f32(acc[mt][2], acc[mt][3], u, true);
            h1f[(size_t)node * 16 + mt * 4 + quad] = (unsigned)u;
        }
        return;
    }

    // ---------- Phase A: bin edges by dst>>8, grouped (staged) writes ----------
    __shared__ int lcnt[KB];
    __shared__ int lexcl[KB];
    __shared__ int lbase[KB];
    __shared__ int stage[512 * EPT_A];
    __shared__ int gaddr[512 * EPT_A];
    __shared__ int wss[8];
    __shared__ int total_s;
    const int tid = threadIdx.x;
    const int lane = tid & 63, wv = tid >> 6;
    const int gseg = blockIdx.x & (SEG - 1);

    for (int i = tid; i < KB; i += 512) lcnt[i] = 0;
    __syncthreads();

    const int e0 = blockIdx.x * 512 * EPT_A;
    int my_s[EPT_A], my_b[EPT_A], my_dl[EPT_A], my_r[EPT_A];
#pragma unroll
    for (int j = 0; j < EPT_A; ++j) {
        const int e = e0 + j * 512 + tid;
        if (e < N_EDGES) {
            const int d = dst[e];
            my_s[j] = src[e];
            my_b[j] = d >> 8;
            my_dl[j] = d & 255;
            my_r[j] = atomicAdd(&lcnt[my_b[j]], 1);   // count AND rank
        } else my_b[j] = -1;
    }
    __syncthreads();

    // wave-shuffle inclusive scan of lcnt -> lexcl (3 barriers total)
    {
        int v = (tid < KB) ? lcnt[tid] : 0;
        v = wave_incl_scan(v, lane);
        if (lane == 63) wss[wv] = v;
        __syncthreads();
        int pre = 0;
        for (int k = 0; k < wv; ++k) pre += wss[k];
        if (tid < KB) lexcl[tid] = v + pre;
        if (tid == KB - 1) total_s = v + pre;
        __syncthreads();
    }
    const int total = total_s;
    if (tid < KB) {
        lexcl[tid] -= lcnt[tid];   // inclusive -> exclusive
        lbase[tid] = (lcnt[tid] > 0) ? atomicAdd(&bcnt16[tid * SEG + gseg], lcnt[tid]) : 0;
    }
    __syncthreads();

    // place edges using saved ranks (plain LDS stores, no atomics)
#pragma unroll
    for (int j = 0; j < EPT_A; ++j) {
        if (my_b[j] >= 0) {
            const int b = my_b[j];
            const int li = lexcl[b] + my_r[j];
            stage[li] = (my_s[j] << 8) | my_dl[j];
            int gp = lbase[b] + my_r[j];
            if (gp >= GCAP) gp = GCAP - 1;
            gaddr[li] = b * BK2 + gseg * GCAP + gp;
        }
    }
    __syncthreads();

    for (int i = tid; i < total; i += 512)
        gbuf[gaddr[i]] = stage[i];
}

// ===== binB_g1: quarter-bucket split (1252 blocks, 4 per bucket) =====
// Each block runs the full sort prefix for its bucket (segment read + hist/rank
// + scan: needed for offsets), but places ONLY its own quarter's edges into
// outb, writes ONLY its quarter's col slice (exact partition), then gathers +
// GEMM2s its 64 nodes. LDS ~31 KB -> 4 blocks/CU (wave cap); grid fills chip.
__global__ __launch_bounds__(512) void binB_g1_kernel(const int* __restrict__ bcnt16,
                                                      const int* __restrict__ gbuf,
                                                      const unsigned* __restrict__ h1f,
                                                      const unsigned* __restrict__ w2t,
                                                      int* __restrict__ rp,
                                                      int* __restrict__ col,
                                                      unsigned* __restrict__ h2f) {
    __shared__ int hist[256];
    __shared__ int excl[256];
    __shared__ int rp_l[260];             // exclusive offsets; [256] = n
    __shared__ int outb[BK_CAP];          // 18.4 KB sorted srcs (own quarter valid)
    __shared__ unsigned aggLds[64 * 36];  // 9.2 KB relu'd bf16 agg (own 64 nodes)
    __shared__ int ngs[SEG];
    __shared__ int wssA[8];
    __shared__ int wssB[8];
    __shared__ int cbase_s;
    const int bb = blockIdx.x >> 2;       // bucket
    const int q  = blockIdx.x & 3;        // quarter (64 nodes)
    const int tid = threadIdx.x;
    const int lane = tid & 63, wv = tid >> 6;

    int bv = 0;
    if (tid < KB) {
#pragma unroll
        for (int g = 0; g < SEG; ++g) bv += min(bcnt16[tid * SEG + g], GCAP);
        bv = min(bv, BK_CAP);
    }
    if (tid < 256) hist[tid] = 0;
    if (tid < SEG) ngs[tid] = min(bcnt16[bb * SEG + tid], GCAP);
    {
        int iv = wave_incl_scan(bv, lane);
        if (lane == 63) wssA[wv] = iv;
        __syncthreads();
        int pre = 0;
        for (int k = 0; k < wv; ++k) pre += wssA[k];
        if (tid == bb) cbase_s = iv + pre - bv;   // exclusive base of own bucket
        __syncthreads();
    }
    const int cbase = cbase_s;
    int n = 0;
#pragma unroll
    for (int g = 0; g < SEG; ++g) n += ngs[g];
    n = min(n, BK_CAP);
    const int* __restrict__ my = gbuf + (size_t)bb * BK2;

    // ---- single pass: read segments (<=1 edge/thread each), rank via atomic ----
    int my_pk[SEG], my_rk[SEG];
#pragma unroll
    for (int g = 0; g < SEG; ++g) {
        my_pk[g] = -1;
        if (tid < ngs[g]) {
            const int pk = my[g * GCAP + tid];
            my_pk[g] = pk;
            my_rk[g] = atomicAdd(&hist[pk & 255], 1);   // count AND rank
        }
    }
    __syncthreads();

    // ---- wave-scan 256 -> exclusive offsets; quarter 0 emits rp; save rp_l ----
    {
        const int h = (tid < 256) ? hist[tid] : 0;
        int ih = wave_incl_scan(h, lane);
        if (lane == 63) wssB[wv] = ih;
        __syncthreads();
        int pre = 0;
        for (int k = 0; k < wv && k < 4; ++k) pre += wssB[k];
        if (tid < 256) {
            const int ex = ih + pre - h;   // exclusive
            excl[tid] = ex;
            rp_l[tid] = ex;
            const int node = bb * 256 + tid;
            if (q == 0 && node <= N_NODES) rp[node] = cbase + ex;
        }
        if (tid == 256) rp_l[256] = n;
        __syncthreads();
    }

    // ---- place ONLY own quarter's edges into outb (no atomics) ----
#pragma unroll
    for (int g = 0; g < SEG; ++g) {
        if (my_pk[g] >= 0) {
            const int pk = my_pk[g];
            const int nl8 = pk & 255;
            if ((nl8 >> 6) == q) {
                const int pos = min(excl[nl8] + my_rk[g], BK_CAP - 1);
                outb[pos] = pk >> 8;
            }
        }
    }
    __syncthreads();
    // col slice for own quarter: positions [rp_l[64q], rp_l[64q+64]) — exact partition
    {
        const int lo = rp_l[q * 64], hi = rp_l[q * 64 + 64];
        for (int i = lo + tid; i < hi; i += 512)
            col[cbase + i] = outb[i];
    }

    // ---- gather (fp8 h1f): own 64 nodes; 8 lanes/node ----
    const int sl8 = tid & 7;
    const int es = sl8 >> 2, cl = sl8 & 3;
    {
        const int l = tid >> 3;                     // 0..63 local to quarter
        const int node_l = q * 64 + l;              // 0..255 in bucket
        const int b0 = rp_l[node_l], e0 = rp_l[node_l + 1];

        v2f acc[8];
#pragma unroll
        for (int k = 0; k < 8; ++k) acc[k] = (v2f){0.f, 0.f};

        for (int pos = b0 + es; pos < e0; pos += 2) {
            const int s = outb[pos];
            const uint4 v = *(const uint4*)(h1f + (size_t)s * 16 + cl * 4);
            acc[0] += __builtin_amdgcn_cvt_pk_f32_fp8((int)v.x, false);
            acc[1] += __builtin_amdgcn_cvt_pk_f32_fp8((int)v.x, true);
            acc[2] += __builtin_amdgcn_cvt_pk_f32_fp8((int)v.y, false);
            acc[3] += __builtin_amdgcn_cvt_pk_f32_fp8((int)v.y, true);
            acc[4] += __builtin_amdgcn_cvt_pk_f32_fp8((int)v.z, false);
            acc[5] += __builtin_amdgcn_cvt_pk_f32_fp8((int)v.z, true);
            acc[6] += __builtin_amdgcn_cvt_pk_f32_fp8((int)v.w, false);
            acc[7] += __builtin_amdgcn_cvt_pk_f32_fp8((int)v.w, true);
        }
        // fold edge-slot 1 -> 0 (lanes sl8<4), distance 4 within the wave
#pragma unroll
        for (int k = 0; k < 8; ++k) {
#pragma unroll
            for (int h = 0; h < 2; ++h)
                acc[k][h] += __shfl_down(acc[k][h], 4, 64);
        }
        if (sl8 < 4) {   // relu; pack 16 ch as 8 bf16-pair u32s (u32 t = ch 2t,2t+1)
            unsigned o8[8];
#pragma unroll
            for (int t = 0; t < 8; ++t) {
                const int k = 2 * (t >> 1) + (t & 1);
                o8[t] = pack_bf2(fmaxf(acc[k][0], 0.f), fmaxf(acc[k][1], 0.f));
            }
            uint4 w0, w1;
            w0.x = o8[0]; w0.y = o8[1]; w0.z = o8[2]; w0.w = o8[3];
            w1.x = o8[4]; w1.y = o8[5]; w1.z = o8[6]; w1.w = o8[7];
            *(uint4*)(aggLds + l * 36 + cl * 8) = w0;
            *(uint4*)(aggLds + l * 36 + cl * 8 + 4) = w1;
        }
    }
    __syncthreads();

    // ---- fused GEMM2: waves 0-3, one 16-node tile each; agg -> MFMA -> h2f ----
    const int wave = tid >> 6;
    const int nl = lane & 15, quad = lane >> 4;
    if (wave < 4) {
        const int l = wave * 16 + nl;               // 0..63 local
        const int node2 = bb * 256 + q * 64 + l;

        v4f c[3];
#pragma unroll
        for (int m = 0; m < 3; ++m) c[m] = (v4f){0.f, 0.f, 0.f, 0.f};

#pragma unroll
        for (int kit = 0; kit < 2; ++kit) {
            U16 bu;
            bu.u = *(const uint4*)(aggLds + l * 36 + kit * 16 + quad * 4);
#pragma unroll
            for (int mt = 0; mt < 3; ++mt) {
                U16 au;
                au.u = *(const uint4*)(w2t + ((mt * 16 + nl) * 32 + kit * 16 + quad * 4));
                c[mt] = __builtin_amdgcn_mfma_f32_16x16x32_bf16(au.s, bu.s, c[mt], 0, 0, 0);
            }
        }
        if (node2 < N_NODES) {
#pragma unroll
            for (int mt = 0; mt < 3; ++mt) {
                const int idx = mt * 4 + quad;
                if (idx < 10) {
                    int u = 0;
                    u = __builtin_amdgcn_cvt_pk_fp8_f32(c[mt][0], c[mt][1], u, false);
                    u = __builtin_amdgcn_cvt_pk_fp8_f32(c[mt][2], c[mt][3], u, true);
                    h2f[(size_t)node2 * 10 + idx] = (unsigned)u;
                }
            }
        }
    }
}

// ==== SpMM2 gather + log_softmax (proven): fp8 table; block = 16 nodes ====
// 4 nodes/wave, 16 lanes/node: 3 edge slots x 5 lanes x uint2 (8 fp8 ch).
__global__ void gather40_ls_kernel(const int* __restrict__ rp, const int* __restrict__ col,
                                   const unsigned* __restrict__ h2f,
                                   float* __restrict__ out) {
    __shared__ int lcol[1024];         // mean 256, 1024 = +48 sigma
    const int tid = threadIdx.x;
    const int lane = tid & 63;
    const int wave = tid >> 6;
    const int sl = lane & 15;
    const int es = sl / 5;            // 0..3 (es==3: lane 15 idle for loads)
    const int cl = sl - es * 5;       // 0..4 (uint2 = 8 fp8 ch)
    const int gbase = lane & 48;      // group base lane (g*16)
    const int nb = blockIdx.x * 16;

    const int seg_b = rp[nb];
    const int seg_n = min(rp[nb + 16] - seg_b, 1024);
    for (int i = tid; i < seg_n; i += 256) lcol[i] = col[seg_b + i];
    __syncthreads();

    const int node = nb + wave * 4 + (lane >> 4);
    const int b = rp[node], e = rp[node + 1];

    v2f a[4];
#pragma unroll
    for (int k = 0; k < 4; ++k) a[k] = (v2f){0.f, 0.f};

    for (int pos = b; __any(pos < e); pos += 24) {
#pragma unroll
        for (int j = 0; j < 8; ++j) {
            const int ei = pos + j * 3 + es;
            if ((es < 3) && (ei < e)) {
                const int o = ei - seg_b;
                const int s = (o < seg_n) ? lcol[o] : col[ei];
                const uint2 v = *(const uint2*)(h2f + (size_t)s * 10 + cl * 2);
                a[0] += __builtin_amdgcn_cvt_pk_f32_fp8((int)v.x, false);
                a[1] += __builtin_amdgcn_cvt_pk_f32_fp8((int)v.x, true);
                a[2] += __builtin_amdgcn_cvt_pk_f32_fp8((int)v.y, false);
                a[3] += __builtin_amdgcn_cvt_pk_f32_fp8((int)v.y, true);
            }
        }
    }
    // fold 3 edge-slots -> lanes sl<5 within each 16-lane group
#pragma unroll
    for (int k = 0; k < 4; ++k) {
#pragma unroll
        for (int h = 0; h < 2; ++h) {
            const float u = __shfl_down(a[k][h], 5, 64);
            const float w = __shfl_down(a[k][h], 10, 64);
            a[k][h] += u + w;
        }
    }

    const bool own = sl < 5;
    float m = -INFINITY;
    if (own) {
#pragma unroll
        for (int k = 0; k < 4; ++k) m = fmaxf(m, fmaxf(a[k][0], a[k][1]));
    }
    const float m0 = __shfl(m, gbase + 0, 64), m1 = __shfl(m, gbase + 1, 64);
    const float m2 = __shfl(m, gbase + 2, 64), m3 = __shfl(m, gbase + 3, 64);
    const float m4 = __shfl(m, gbase + 4, 64);
    const float gm = fmaxf(fmaxf(fmaxf(m0, m1), fmaxf(m2, m3)), m4);

    float s = 0.f;
    if (own) {
#pragma unroll
        for (int k = 0; k < 4; ++k)
            s += __expf(a[k][0] - gm) + __expf(a[k][1] - gm);
    }
    const float s0 = __shfl(s, gbase + 0, 64), s1 = __shfl(s, gbase + 1, 64);
    const float s2 = __shfl(s, gbase + 2, 64), s3 = __shfl(s, gbase + 3, 64);
    const float s4 = __shfl(s, gbase + 4, 64);
    const float ls = __logf(s0 + s1 + s2 + s3 + s4) + gm;

    if (own) {
        float* op = out + (size_t)node * OUT_C + cl * 8;
        *(float4*)op = make_float4(a[0][0] - ls, a[0][1] - ls, a[1][0] - ls, a[1][1] - ls);
        *(float4*)(op + 4) = make_float4(a[2][0] - ls, a[2][1] - ls, a[3][0] - ls, a[3][1] - ls);
    }
}

extern "C" void kernel_launch(void* const* d_in, const int* in_sizes, int n_in,
                              void* d_out, int out_size, void* d_ws, size_t ws_size,
                              hipStream_t stream) {
    const float* x  = (const float*)d_in[0];
    const int* eidx = (const int*)d_in[1];
    const float* W1 = (const float*)d_in[2];
    const float* W2 = (const float*)d_in[3];
    float* out = (float*)d_out;

    const int* src = eidx;             // edge_index[0]
    const int* dst = eidx + N_EDGES;   // edge_index[1]

    // Workspace (u32 units):
    //   h1f  [80000*16]  5.12 MB (fp8 e4m3, node-major, 16 u32/node)
    //   h2f  [80000*10]  3.20 MB (fp8 e4m3)
    //   gbuf [313*6656]  8.33 MB (packed edges, 16 shard segments per bucket)
    //   col  [1.28M], rp [80004], bcnt16 [5008], w1t, w2t
    unsigned* h1f    = (unsigned*)d_ws;
    unsigned* h2f    = h1f + (size_t)N_NODES * 16;
    int*      gbuf   = (int*)(h2f + (size_t)N_NODES * 10);
    int*      col    = gbuf + (size_t)KB * BK2;
    int*      rp     = col + N_EDGES;
    int*      bcnt16 = rp + 80004;
    unsigned* w1t    = (unsigned*)(bcnt16 + SEG * KB + 8);
    unsigned* w2t    = w1t + 4096;

    // --- prep (+zero bcnt16), overlapped {edge binning | GEMM1} ---
    prep_w_kernel<<<20, 256, 0, stream>>>(W1, W2, w1t, w2t, bcnt16);
    binA_gemm1_kernel<<<NBLK_A + NBLK_G1, 512, 0, stream>>>(src, dst, bcnt16, gbuf, x, w1t, h1f);

    // --- fused {sort -> rp/col -> gather1 -> GEMM2} (4 blocks/bucket), then gather2 ---
    binB_g1_kernel<<<4 * KB, 512, 0, stream>>>(bcnt16, gbuf, h1f, w2t, rp, col, h2f);
    gather40_ls_kernel<<<N_NODES / 16, 256, 0, stream>>>(rp, col, h2f, out);
}

// Round 18
// 157.481 us; speedup vs baseline: 1.0611x; 1.0611x over previous
//
#include <hip/hip_runtime.h>
#include <hip/hip_bf16.h>
#include <math.h>

#define N_NODES 80000
#define N_EDGES 1280000
#define IN_C 128
#define HID_C 64
#define OUT_C 40

// Bucketed binning: bucket = dst >> 8 (256 nodes per bucket)
#define KB 313            // ceil(80000 / 256)
#define BK_CAP 4600       // per-bucket total cap (mean 4090, sigma ~64 -> 8 sigma)
#define SEG 16            // counter shards per bucket (g = blockIdx & 15)
#define GCAP 416          // per-(bucket,shard) slot cap (mean 256, sigma ~16 -> 10 sigma)
#define BK2 (SEG * GCAP)  // 6656 slots per bucket in gbuf
#define EPT_A 8           // edges per thread in phase A (512 thr -> 4096 per WG)
#define NBLK_A 313        // ceil(1280000 / 4096)
#define NBLK_G1 625       // N_NODES / 128 (8 waves x 16 nodes per block)

// ---- bf16 helpers (storage bf16, math fp32) ----
__device__ __forceinline__ float bf_lo(unsigned u) {
    union { unsigned i; float f; } c; c.i = u << 16; return c.f;
}
__device__ __forceinline__ float bf_hi(unsigned u) {
    union { unsigned i; float f; } c; c.i = u & 0xffff0000u; return c.f;
}
__device__ __forceinline__ unsigned pack_bf2(float a, float b) {  // RTNE
    union { float f; unsigned i; } ca, cb; ca.f = a; cb.f = b;
    unsigned ra = (ca.i + 0x7fffu + ((ca.i >> 16) & 1u)) >> 16;
    unsigned rb = (cb.i + 0x7fffu + ((cb.i >> 16) & 1u)) >> 16;
    return ra | (rb << 16);
}

typedef short v8s __attribute__((ext_vector_type(8)));   // 8 bf16 = 4 VGPR
typedef float v4f __attribute__((ext_vector_type(4)));
typedef float v2f __attribute__((ext_vector_type(2)));
union U16 { uint4 u; v8s s; };

// wave-inclusive scan (64 lanes, no barriers)
__device__ __forceinline__ int wave_incl_scan(int v, int lane) {
#pragma unroll
    for (int o = 1; o < 64; o <<= 1) {
        const int t = __shfl_up(v, o, 64);
        if (lane >= o) v += t;
    }
    return v;
}

// ======== prep: W1^T, W2^T to bf16 + zero bcnt16 (20 blocks) ========
__global__ void prep_w_kernel(const float* __restrict__ W1, const float* __restrict__ W2,
                              unsigned* __restrict__ w1t, unsigned* __restrict__ w2t,
                              int* __restrict__ bcnt16) {
    const int g = blockIdx.x * 256 + threadIdx.x;     // 0..5119
    if (g < SEG * KB) bcnt16[g] = 0;
    if (g < 4096) {   // w1t
        const int wcol = g >> 6, kk = g & 63;
        w1t[g] = pack_bf2(W1[(2 * kk) * HID_C + wcol], W1[(2 * kk + 1) * HID_C + wcol]);
    }
    if (g < 1536) {   // w2t
        const int wcol = g >> 5, kk = g & 31;
        w2t[g] = (wcol < OUT_C)
            ? pack_bf2(W2[(2 * kk) * OUT_C + wcol], W2[(2 * kk + 1) * OUT_C + wcol])
            : 0u;
    }
}

// ========== Combined launch: blocks [0,NBLK_A) bin edges; rest do GEMM1 ==========
// r12-proven configuration: scalar strided edge loads (issue-order interleave
// with rank atomics), rank trick (single LDS-atomic pass), staged gbuf writes
// (LDS stage/gaddr -> coalesced 64-lane burst sweep).
__global__ __launch_bounds__(512) void binA_gemm1_kernel(const int* __restrict__ src,
                                                         const int* __restrict__ dst,
                                                         int* __restrict__ bcnt16,
                                                         int* __restrict__ gbuf,
                                                         const float* __restrict__ x,
                                                         const unsigned* __restrict__ w1t,
                                                         unsigned* __restrict__ h1f) {
    if (blockIdx.x >= NBLK_A) {
        const int tid = threadIdx.x;
        const int wave = tid >> 6, lane = tid & 63;
        const int nl = lane & 15, quad = lane >> 4;
        const int node = ((blockIdx.x - NBLK_A) * 8 + wave) * 16 + nl;

        float4 xv[8];
#pragma unroll
        for (int kit = 0; kit < 4; ++kit) {
            const float* xp = x + (size_t)node * IN_C + kit * 32 + quad * 8;
            xv[kit * 2]     = *(const float4*)xp;
            xv[kit * 2 + 1] = *(const float4*)(xp + 4);
        }

        v4f acc[4];
#pragma unroll
        for (int q = 0; q < 4; ++q) acc[q] = (v4f){0.f, 0.f, 0.f, 0.f};

#pragma unroll
        for (int kit = 0; kit < 4; ++kit) {
            const float4 lo = xv[kit * 2], hi = xv[kit * 2 + 1];
            U16 bu;
            bu.u.x = pack_bf2(lo.x, lo.y); bu.u.y = pack_bf2(lo.z, lo.w);
            bu.u.z = pack_bf2(hi.x, hi.y); bu.u.w = pack_bf2(hi.z, hi.w);
#pragma unroll
            for (int mt = 0; mt < 4; ++mt) {
                U16 au;
                au.u = *(const uint4*)(w1t + ((mt * 16 + nl) * 64 + kit * 16 + quad * 4));
                acc[mt] = __builtin_amdgcn_mfma_f32_16x16x32_bf16(au.s, bu.s, acc[mt], 0, 0, 0);
            }
        }
#pragma unroll
        for (int mt = 0; mt < 4; ++mt) {
            int u = 0;
            u = __builtin_amdgcn_cvt_pk_fp8_f32(acc[mt][0], acc[mt][1], u, false);
            u = __builtin_amdgcn_cvt_pk_fp8_f32(acc[mt][2], acc[mt][3], u, true);
            h1f[(size_t)node * 16 + mt * 4 + quad] = (unsigned)u;
        }
        return;
    }

    // ---------- Phase A: bin edges by dst>>8, grouped (staged) writes ----------
    __shared__ int lcnt[KB];
    __shared__ int lexcl[KB];
    __shared__ int lbase[KB];
    __shared__ int stage[512 * EPT_A];
    __shared__ int gaddr[512 * EPT_A];
    __shared__ int wss[8];
    __shared__ int total_s;
    const int tid = threadIdx.x;
    const int lane = tid & 63, wv = tid >> 6;
    const int gseg = blockIdx.x & (SEG - 1);

    for (int i = tid; i < KB; i += 512) lcnt[i] = 0;
    __syncthreads();

    const int e0 = blockIdx.x * 512 * EPT_A;
    int my_s[EPT_A], my_b[EPT_A], my_dl[EPT_A], my_r[EPT_A];
#pragma unroll
    for (int j = 0; j < EPT_A; ++j) {
        const int e = e0 + j * 512 + tid;
        if (e < N_EDGES) {
            const int d = dst[e];
            my_s[j] = src[e];
            my_b[j] = d >> 8;
            my_dl[j] = d & 255;
            my_r[j] = atomicAdd(&lcnt[my_b[j]], 1);   // count AND rank
        } else my_b[j] = -1;
    }
    __syncthreads();

    // wave-shuffle inclusive scan of lcnt -> lexcl (3 barriers total)
    {
        int v = (tid < KB) ? lcnt[tid] : 0;
        v = wave_incl_scan(v, lane);
        if (lane == 63) wss[wv] = v;
        __syncthreads();
        int pre = 0;
        for (int k = 0; k < wv; ++k) pre += wss[k];
        if (tid < KB) lexcl[tid] = v + pre;
        if (tid == KB - 1) total_s = v + pre;
        __syncthreads();
    }
    const int total = total_s;
    if (tid < KB) {
        lexcl[tid] -= lcnt[tid];   // inclusive -> exclusive
        lbase[tid] = (lcnt[tid] > 0) ? atomicAdd(&bcnt16[tid * SEG + gseg], lcnt[tid]) : 0;
    }
    __syncthreads();

    // place edges using saved ranks (plain LDS stores, no atomics)
#pragma unroll
    for (int j = 0; j < EPT_A; ++j) {
        if (my_b[j] >= 0) {
            const int b = my_b[j];
            const int li = lexcl[b] + my_r[j];
            stage[li] = (my_s[j] << 8) | my_dl[j];
            int gp = lbase[b] + my_r[j];
            if (gp >= GCAP) gp = GCAP - 1;
            gaddr[li] = b * BK2 + gseg * GCAP + gp;
        }
    }
    __syncthreads();

    for (int i = tid; i < total; i += 512)
        gbuf[gaddr[i]] = stage[i];
}

// ===== binB_g1: half-bucket split for occupancy (626 blocks, 2 per bucket) =====
// Block pair (2b, 2b+1): both run the cheap sort phase for bucket b (redundant,
// LDS-local); half 0 emits rp/col; each half gathers + GEMM2s its own 128 nodes.
// aggLds halves to 128x36 -> ~40 KB LDS -> ~4 blocks/CU (was ~1.2 at 313 blocks).
__global__ __launch_bounds__(512) void binB_g1_kernel(const int* __restrict__ bcnt16,
                                                      const int* __restrict__ gbuf,
                                                      const unsigned* __restrict__ h1f,
                                                      const unsigned* __restrict__ w2t,
                                                      int* __restrict__ rp,
                                                      int* __restrict__ col,
                                                      unsigned* __restrict__ h2f) {
    __shared__ int hist[256];
    __shared__ int excl[256];
    __shared__ int rp_l[260];             // exclusive offsets; [256] = n
    __shared__ int outb[BK_CAP];          // 18.4 KB sorted srcs (full bucket)
    __shared__ unsigned aggLds[128 * 36]; // 18.4 KB relu'd bf16 agg (own half)
    __shared__ int ngs[SEG];
    __shared__ int wssA[8];
    __shared__ int wssB[8];
    __shared__ int cbase_s;
    const int bb = blockIdx.x >> 1;       // bucket
    const int half = blockIdx.x & 1;      // which 128-node half we own
    const int tid = threadIdx.x;
    const int lane = tid & 63, wv = tid >> 6;

    int bv = 0;
    if (tid < KB) {
#pragma unroll
        for (int g = 0; g < SEG; ++g) bv += min(bcnt16[tid * SEG + g], GCAP);
        bv = min(bv, BK_CAP);
    }
    if (tid < 256) hist[tid] = 0;
    if (tid < SEG) ngs[tid] = min(bcnt16[bb * SEG + tid], GCAP);
    {
        int iv = wave_incl_scan(bv, lane);
        if (lane == 63) wssA[wv] = iv;
        __syncthreads();
        int pre = 0;
        for (int k = 0; k < wv; ++k) pre += wssA[k];
        if (tid == bb) cbase_s = iv + pre - bv;   // exclusive base of own bucket
        __syncthreads();
    }
    const int cbase = cbase_s;
    int n = 0;
#pragma unroll
    for (int g = 0; g < SEG; ++g) n += ngs[g];
    n = min(n, BK_CAP);
    const int* __restrict__ my = gbuf + (size_t)bb * BK2;

    // ---- single pass: read segments (<=1 edge/thread each), rank via atomic ----
    int my_pk[SEG], my_rk[SEG];
#pragma unroll
    for (int g = 0; g < SEG; ++g) {
        my_pk[g] = -1;
        if (tid < ngs[g]) {
            const int pk = my[g * GCAP + tid];
            my_pk[g] = pk;
            my_rk[g] = atomicAdd(&hist[pk & 255], 1);   // count AND rank
        }
    }
    __syncthreads();

    // ---- wave-scan 256 -> exclusive offsets; half 0 emits rp; save rp_l ----
    {
        const int h = (tid < 256) ? hist[tid] : 0;
        int ih = wave_incl_scan(h, lane);
        if (lane == 63) wssB[wv] = ih;
        __syncthreads();
        int pre = 0;
        for (int k = 0; k < wv && k < 4; ++k) pre += wssB[k];
        if (tid < 256) {
            const int ex = ih + pre - h;   // exclusive
            excl[tid] = ex;
            rp_l[tid] = ex;
            const int node = bb * 256 + tid;
            if (half == 0 && node <= N_NODES) rp[node] = cbase + ex;
        }
        if (tid == 256) rp_l[256] = n;
        __syncthreads();
    }

    // ---- place into outb using saved ranks (no atomics) ----
#pragma unroll
    for (int g = 0; g < SEG; ++g) {
        if (my_pk[g] >= 0) {
            const int pk = my_pk[g];
            const int pos = min(excl[pk & 255] + my_rk[g], BK_CAP - 1);
            outb[pos] = pk >> 8;
        }
    }
    __syncthreads();
    if (half == 0) {   // col emitted once per bucket (same multiset per node)
        for (int i = tid; i < n; i += 512)
            col[cbase + i] = outb[i];
    }

    // ---- gather (fp8 h1f): 2 passes x 64 nodes of OWN half; 8 lanes/node ----
    const int sl8 = tid & 7;
    const int es = sl8 >> 2, cl = sl8 & 3;
#pragma unroll
    for (int p = 0; p < 2; ++p) {
        const int l = p * 64 + (tid >> 3);          // 0..127 local to half
        const int node_l = half * 128 + l;          // 0..255 in bucket
        const int b0 = rp_l[node_l], e0 = rp_l[node_l + 1];

        v2f acc[8];
#pragma unroll
        for (int k = 0; k < 8; ++k) acc[k] = (v2f){0.f, 0.f};

        for (int pos = b0 + es; pos < e0; pos += 2) {
            const int s = outb[pos];
            const uint4 v = *(const uint4*)(h1f + (size_t)s * 16 + cl * 4);
            acc[0] += __builtin_amdgcn_cvt_pk_f32_fp8((int)v.x, false);
            acc[1] += __builtin_amdgcn_cvt_pk_f32_fp8((int)v.x, true);
            acc[2] += __builtin_amdgcn_cvt_pk_f32_fp8((int)v.y, false);
            acc[3] += __builtin_amdgcn_cvt_pk_f32_fp8((int)v.y, true);
            acc[4] += __builtin_amdgcn_cvt_pk_f32_fp8((int)v.z, false);
            acc[5] += __builtin_amdgcn_cvt_pk_f32_fp8((int)v.z, true);
            acc[6] += __builtin_amdgcn_cvt_pk_f32_fp8((int)v.w, false);
            acc[7] += __builtin_amdgcn_cvt_pk_f32_fp8((int)v.w, true);
        }
        // fold edge-slot 1 -> 0 (lanes sl8<4), distance 4 within the wave
#pragma unroll
        for (int k = 0; k < 8; ++k) {
#pragma unroll
            for (int h = 0; h < 2; ++h)
                acc[k][h] += __shfl_down(acc[k][h], 4, 64);
        }
        if (sl8 < 4) {   // relu; pack 16 ch as 8 bf16-pair u32s (u32 t = ch 2t,2t+1)
            unsigned o8[8];
#pragma unroll
            for (int t = 0; t < 8; ++t) {
                const int k = 2 * (t >> 1) + (t & 1);
                o8[t] = pack_bf2(fmaxf(acc[k][0], 0.f), fmaxf(acc[k][1], 0.f));
            }
            uint4 w0, w1;
            w0.x = o8[0]; w0.y = o8[1]; w0.z = o8[2]; w0.w = o8[3];
            w1.x = o8[4]; w1.y = o8[5]; w1.z = o8[6]; w1.w = o8[7];
            *(uint4*)(aggLds + l * 36 + cl * 8) = w0;
            *(uint4*)(aggLds + l * 36 + cl * 8 + 4) = w1;
        }
    }
    __syncthreads();

    // ---- fused GEMM2: 8 waves x 16 nodes = own 128; agg -> MFMA -> fp8 h2f ----
    const int wave = tid >> 6;
    const int nl = lane & 15, quad = lane >> 4;
    {
        const int l = wave * 16 + nl;               // 0..127 local
        const int node2 = bb * 256 + half * 128 + l;

        v4f c[3];
#pragma unroll
        for (int m = 0; m < 3; ++m) c[m] = (v4f){0.f, 0.f, 0.f, 0.f};

#pragma unroll
        for (int kit = 0; kit < 2; ++kit) {
            U16 bu;
            bu.u = *(const uint4*)(aggLds + l * 36 + kit * 16 + quad * 4);
#pragma unroll
            for (int mt = 0; mt < 3; ++mt) {
                U16 au;
                au.u = *(const uint4*)(w2t + ((mt * 16 + nl) * 32 + kit * 16 + quad * 4));
                c[mt] = __builtin_amdgcn_mfma_f32_16x16x32_bf16(au.s, bu.s, c[mt], 0, 0, 0);
            }
        }
        if (node2 < N_NODES) {
#pragma unroll
            for (int mt = 0; mt < 3; ++mt) {
                const int idx = mt * 4 + quad;
                if (idx < 10) {
                    int u = 0;
                    u = __builtin_amdgcn_cvt_pk_fp8_f32(c[mt][0], c[mt][1], u, false);
                    u = __builtin_amdgcn_cvt_pk_fp8_f32(c[mt][2], c[mt][3], u, true);
                    h2f[(size_t)node2 * 10 + idx] = (unsigned)u;
                }
            }
        }
    }
}

// ==== SpMM2 gather + log_softmax (proven): fp8 table; block = 16 nodes ====
// 4 nodes/wave, 16 lanes/node: 3 edge slots x 5 lanes x uint2 (8 fp8 ch).
__global__ void gather40_ls_kernel(const int* __restrict__ rp, const int* __restrict__ col,
                                   const unsigned* __restrict__ h2f,
                                   float* __restrict__ out) {
    __shared__ int lcol[1024];         // mean 256, 1024 = +48 sigma
    const int tid = threadIdx.x;
    const int lane = tid & 63;
    const int wave = tid >> 6;
    const int sl = lane & 15;
    const int es = sl / 5;            // 0..3 (es==3: lane 15 idle for loads)
    const int cl = sl - es * 5;       // 0..4 (uint2 = 8 fp8 ch)
    const int gbase = lane & 48;      // group base lane (g*16)
    const int nb = blockIdx.x * 16;

    const int seg_b = rp[nb];
    const int seg_n = min(rp[nb + 16] - seg_b, 1024);
    for (int i = tid; i < seg_n; i += 256) lcol[i] = col[seg_b + i];
    __syncthreads();

    const int node = nb + wave * 4 + (lane >> 4);
    const int b = rp[node], e = rp[node + 1];

    v2f a[4];
#pragma unroll
    for (int k = 0; k < 4; ++k) a[k] = (v2f){0.f, 0.f};

    for (int pos = b; __any(pos < e); pos += 24) {
#pragma unroll
        for (int j = 0; j < 8; ++j) {
            const int ei = pos + j * 3 + es;
            if ((es < 3) && (ei < e)) {
                const int o = ei - seg_b;
                const int s = (o < seg_n) ? lcol[o] : col[ei];
                const uint2 v = *(const uint2*)(h2f + (size_t)s * 10 + cl * 2);
                a[0] += __builtin_amdgcn_cvt_pk_f32_fp8((int)v.x, false);
                a[1] += __builtin_amdgcn_cvt_pk_f32_fp8((int)v.x, true);
                a[2] += __builtin_amdgcn_cvt_pk_f32_fp8((int)v.y, false);
                a[3] += __builtin_amdgcn_cvt_pk_f32_fp8((int)v.y, true);
            }
        }
    }
    // fold 3 edge-slots -> lanes sl<5 within each 16-lane group
#pragma unroll
    for (int k = 0; k < 4; ++k) {
#pragma unroll
        for (int h = 0; h < 2; ++h) {
            const float u = __shfl_down(a[k][h], 5, 64);
            const float w = __shfl_down(a[k][h], 10, 64);
            a[k][h] += u + w;
        }
    }

    const bool own = sl < 5;
    float m = -INFINITY;
    if (own) {
#pragma unroll
        for (int k = 0; k < 4; ++k) m = fmaxf(m, fmaxf(a[k][0], a[k][1]));
    }
    const float m0 = __shfl(m, gbase + 0, 64), m1 = __shfl(m, gbase + 1, 64);
    const float m2 = __shfl(m, gbase + 2, 64), m3 = __shfl(m, gbase + 3, 64);
    const float m4 = __shfl(m, gbase + 4, 64);
    const float gm = fmaxf(fmaxf(fmaxf(m0, m1), fmaxf(m2, m3)), m4);

    float s = 0.f;
    if (own) {
#pragma unroll
        for (int k = 0; k < 4; ++k)
            s += __expf(a[k][0] - gm) + __expf(a[k][1] - gm);
    }
    const float s0 = __shfl(s, gbase + 0, 64), s1 = __shfl(s, gbase + 1, 64);
    const float s2 = __shfl(s, gbase + 2, 64), s3 = __shfl(s, gbase + 3, 64);
    const float s4 = __shfl(s, gbase + 4, 64);
    const float ls = __logf(s0 + s1 + s2 + s3 + s4) + gm;

    if (own) {
        float* op = out + (size_t)node * OUT_C + cl * 8;
        *(float4*)op = make_float4(a[0][0] - ls, a[0][1] - ls, a[1][0] - ls, a[1][1] - ls);
        *(float4*)(op + 4) = make_float4(a[2][0] - ls, a[2][1] - ls, a[3][0] - ls, a[3][1] - ls);
    }
}

extern "C" void kernel_launch(void* const* d_in, const int* in_sizes, int n_in,
                              void* d_out, int out_size, void* d_ws, size_t ws_size,
                              hipStream_t stream) {
    const float* x  = (const float*)d_in[0];
    const int* eidx = (const int*)d_in[1];
    const float* W1 = (const float*)d_in[2];
    const float* W2 = (const float*)d_in[3];
    float* out = (float*)d_out;

    const int* src = eidx;             // edge_index[0]
    const int* dst = eidx + N_EDGES;   // edge_index[1]

    // Workspace (u32 units):
    //   h1f  [80000*16]  5.12 MB (fp8 e4m3, node-major, 16 u32/node)
    //   h2f  [80000*10]  3.20 MB (fp8 e4m3)
    //   gbuf [313*6656]  8.33 MB (packed edges, 16 shard segments per bucket)
    //   col  [1.28M], rp [80004], bcnt16 [5008], w1t, w2t
    unsigned* h1f    = (unsigned*)d_ws;
    unsigned* h2f    = h1f + (size_t)N_NODES * 16;
    int*      gbuf   = (int*)(h2f + (size_t)N_NODES * 10);
    int*      col    = gbuf + (size_t)KB * BK2;
    int*      rp     = col + N_EDGES;
    int*      bcnt16 = rp + 80004;
    unsigned* w1t    = (unsigned*)(bcnt16 + SEG * KB + 8);
    unsigned* w2t    = w1t + 4096;

    // --- prep (+zero bcnt16), overlapped {edge binning | GEMM1} ---
    prep_w_kernel<<<20, 256, 0, stream>>>(W1, W2, w1t, w2t, bcnt16);
    binA_gemm1_kernel<<<NBLK_A + NBLK_G1, 512, 0, stream>>>(src, dst, bcnt16, gbuf, x, w1t, h1f);

    // --- fused {sort -> rp/col -> gather1 -> GEMM2} (2 blocks/bucket), then gather2 ---
    binB_g1_kernel<<<2 * KB, 512, 0, stream>>>(bcnt16, gbuf, h1f, w2t, rp, col, h2f);
    gather40_ls_kernel<<<N_NODES / 16, 256, 0, stream>>>(rp, col, h2f, out);
}